// Round 3
// baseline (610.705 us; speedup 1.0000x reference)
//
#include <hip/hip_runtime.h>
#include <hip/hip_bf16.h>

// DecoderBlock: h_t = tanh(x_t @ U + h_{t-1} @ V + b)
// BZ=256, SEQ=512, IN=HID=256. fp32 in/out.
//
// prep_B : U (fp32) -> bf16 B-fragment-ordered buffer (128 KB). (unchanged)
// xu_gemm: REWRITTEN. BM=128 x BN=256 (full width, X read once), BK=32.
//          X staged through LDS with coalesced 128B row-segments and XOR
//          slot swizzle (conflict-free b128 frag reads), reg double-buffer,
//          one LDS barrier per K-step. Fixes ~4x HBM over-fetch of the old
//          direct row-strided float4 A-loads.
// rnn_rec: REWRITTEN. k-split across 4 waves (wave w owns k in [64w,64w+64)):
//          A-frag = 2 ds_read_b128 per wave (was 8 per wave x 8 waves),
//          32 MFMAs -> 16 col-partials; quad-deduped LDS partial write,
//          cross-wave reduce by 256 threads; 2 LDS-only barriers per step.

#define SEQn 512
#define HIDn 256

typedef __attribute__((ext_vector_type(4))) float    floatx4;
typedef __attribute__((ext_vector_type(8))) short    short8;
typedef __attribute__((ext_vector_type(8))) _Float16 half8;

// LDS-only barrier: drain LDS ops, then sync. Global loads/stores remain
// in flight across the barrier (their consumers get compiler vmcnt waits).
#define LDS_BARRIER() asm volatile("s_waitcnt lgkmcnt(0)\n\ts_barrier" ::: "memory")

__device__ __forceinline__ short f2bf(float f) {
    __hip_bfloat16 h = __float2bfloat16(f);
    return *reinterpret_cast<short*>(&h);
}

// ---------------------------------------------------------------------------
// Pack U[k][n] -> wsB chunks: chunk idx = (kb*4 + q)*256 + n holds
// U[kb*32 + q*8 + j][n] (j=0..7) as bf16. 8192 chunks x 16 B = 128 KB.
// ---------------------------------------------------------------------------
__global__ void prep_B(const float* __restrict__ U, short* __restrict__ wsB) {
    int idx = blockIdx.x * 256 + threadIdx.x;   // 0..8191
    int n  = idx & 255;
    int q  = (idx >> 8) & 3;
    int kb = idx >> 10;
    int k0 = kb * 32 + q * 8;
    short8 c;
    #pragma unroll
    for (int j = 0; j < 8; j++)
        c[j] = f2bf(U[(size_t)(k0 + j) * 256 + n]);
    *(short8*)(wsB + (size_t)idx * 8) = c;
}

// ---------------------------------------------------------------------------
// MFMA GEMM: block tile 128 rows x 256 cols (full N), 4 waves, BK=32.
// Wave w owns rows [32w, 32w+32) (2 m-tiles) x all 256 cols (16 n-tiles).
// X staged in LDS: row-major [128][32] f32, 4-float slots XOR-swizzled
// slot' = g ^ (row & 7). Stage writes linear (thread t -> dword 4t, slot
// t&7, source col-group (t&7)^((t>>3)&7)) => both write and frag-read are
// bank-conflict-free. Reg double-buffer, one LDS barrier per K-step.
// ---------------------------------------------------------------------------
__global__ __launch_bounds__(256, 2)
void xu_gemm(const float* __restrict__ X, const short* __restrict__ wsB,
             const float* __restrict__ bias, float* __restrict__ out)
{
    __shared__ float Xlds[2][4096];     // 2 x 16 KB

    const int tid = threadIdx.x;
    const int l   = tid & 63;
    const int w   = tid >> 6;          // wave 0..3
    const int lr  = l & 15;
    const int q   = l >> 4;
    const int m0  = blockIdx.x * 128;

    // staging source: chunk j covers rows 32j..32j+31; thread t handles
    // row 32j + (t>>3), 16B col-group g_src = (t&7) ^ ((t>>3)&7)
    const int srow = tid >> 3;                       // 0..31
    const int sgrp = (tid & 7) ^ (srow & 7);
    const float* xbase = X + (size_t)(m0 + srow) * 256 + 4 * sgrp;

    floatx4 acc[2][16];
    #pragma unroll
    for (int mt = 0; mt < 2; mt++)
        #pragma unroll
        for (int nt = 0; nt < 16; nt++)
            acc[mt][nt] = (floatx4){0.f, 0.f, 0.f, 0.f};

    // prologue: stage kb=0 into buf 0
    float4 st[4];
    #pragma unroll
    for (int j = 0; j < 4; j++)
        st[j] = *(const float4*)(xbase + (size_t)(32 * j) * 256);
    #pragma unroll
    for (int j = 0; j < 4; j++)
        *(float4*)&Xlds[0][j * 1024 + 4 * tid] = st[j];
    LDS_BARRIER();

    #pragma unroll
    for (int kb = 0; kb < 8; kb++) {
        const int cur = kb & 1;
        if (kb < 7) {   // issue next-tile loads early; hidden under MFMA phase
            #pragma unroll
            for (int j = 0; j < 4; j++)
                st[j] = *(const float4*)(xbase + (size_t)(32 * j) * 256 + (kb + 1) * 32);
        }

        // A fragments from LDS (swizzled slots, conflict-free b128)
        short8 af[2];
        #pragma unroll
        for (int mt = 0; mt < 2; mt++) {
            const int row = 32 * w + 16 * mt + lr;
            const int g0 = (2 * q) ^ (row & 7);
            const int g1 = (2 * q + 1) ^ (row & 7);
            float4 a0 = *(const float4*)&Xlds[cur][row * 32 + 4 * g0];
            float4 a1 = *(const float4*)&Xlds[cur][row * 32 + 4 * g1];
            af[mt][0] = f2bf(a0.x); af[mt][1] = f2bf(a0.y);
            af[mt][2] = f2bf(a0.z); af[mt][3] = f2bf(a0.w);
            af[mt][4] = f2bf(a1.x); af[mt][5] = f2bf(a1.y);
            af[mt][6] = f2bf(a1.z); af[mt][7] = f2bf(a1.w);
        }

        #pragma unroll
        for (int nt = 0; nt < 16; nt++) {
            short8 bfr = *(const short8*)(wsB +
                ((size_t)(kb * 4 + q) * 256 + 16 * nt + lr) * 8);
            acc[0][nt] = __builtin_amdgcn_mfma_f32_16x16x32_bf16(af[0], bfr, acc[0][nt], 0, 0, 0);
            acc[1][nt] = __builtin_amdgcn_mfma_f32_16x16x32_bf16(af[1], bfr, acc[1][nt], 0, 0, 0);
        }

        if (kb < 7) {   // write next tile into the other buffer
            #pragma unroll
            for (int j = 0; j < 4; j++)
                *(float4*)&Xlds[cur ^ 1][j * 1024 + 4 * tid] = st[j];
        }
        LDS_BARRIER();
    }

    #pragma unroll
    for (int nt = 0; nt < 16; nt++) {
        float bv = bias[16 * nt + lr];
        #pragma unroll
        for (int mt = 0; mt < 2; mt++) {
            #pragma unroll
            for (int r = 0; r < 4; r++) {
                int row = m0 + 32 * w + 16 * mt + 4 * q + r;
                out[(size_t)row * 256 + 16 * nt + lr] = acc[mt][nt][r] + bv;
            }
        }
    }
}

// ---------------------------------------------------------------------------
// Recurrence via MFMA, k-split across waves. 1 WG per batch row, 256 thr.
// Wave w owns k in [64w, 64w+64) as 2 K=32 chunks; computes partial sums
// for ALL 256 cols (16 n-tiles). A-frag: h-slice broadcast to all 16 m-rows
// (2 ds_read_b128/wave). B-frag: vf[nt][c][j] = fp16 V[64w+32c+8q+j][16nt+lr]
// (128 VGPR, preloaded). C rows identical -> acc[nt][0] = partial(col).
// Quad-deduped partial write -> barrier -> 256-thread cross-wave reduce,
// tanh, h write -> barrier. Two LDS-only barriers per step.
// ---------------------------------------------------------------------------
__global__ __launch_bounds__(256, 1)
void rnn_rec(const float* __restrict__ enc, const float* __restrict__ V,
             float* __restrict__ out)
{
    __shared__ _Float16 hbuf[2][HIDn];   // ping-pong h, 1 KB
    __shared__ float    part[4][HIDn];   // per-wave partials, 4 KB

    const int tid = threadIdx.x;         // 0..255
    const int w   = tid >> 6;            // wave 0..3
    const int l   = tid & 63;
    const int lr  = l & 15;
    const int q   = l >> 4;
    const int b   = blockIdx.x;

    // ---- preload V as fp16 B-fragments: 32 frags x 8 halves = 128 VGPR ----
    half8 vf[16][2];
    #pragma unroll
    for (int nt = 0; nt < 16; nt++) {
        #pragma unroll
        for (int c = 0; c < 2; c++) {
            const float* vp = V + (size_t)(64 * w + 32 * c + 8 * q) * HIDn + 16 * nt + lr;
            half8 tmp;
            #pragma unroll
            for (int j = 0; j < 8; j++)
                tmp[j] = (_Float16)vp[(size_t)j * HIDn];
            vf[nt][c] = tmp;
        }
    }

    float* outEnc = out + (size_t)b * HIDn;
    float* outDec = out + (size_t)65536 + (size_t)b * SEQn * HIDn;

    // ---- h0 init + encoder passthrough ----
    {
        float h0 = enc[(size_t)b * HIDn + tid];
        outEnc[tid]  = h0;
        hbuf[0][tid] = (_Float16)h0;
    }

    // ---- XU prefetch pipeline, depth 2 (thread owns col tid) ----
    float xu_cur = outDec[tid];
    float xu_nx  = outDec[HIDn + tid];

    const floatx4 zero4 = {0.f, 0.f, 0.f, 0.f};

    LDS_BARRIER();

    int p = 0;
    for (int t = 0; t < SEQn; t++) {
        float pf = 0.f;
        if (t + 2 < SEQn) pf = outDec[(size_t)(t + 2) * HIDn + tid];

        // A fragments: af_c[j] = h[64w + 32c + 8q + j] (broadcast rows)
        half8 af0 = *(const half8*)&hbuf[p][64 * w + 8 * q];
        half8 af1 = *(const half8*)&hbuf[p][64 * w + 32 + 8 * q];

        floatx4 acc[16];
        #pragma unroll
        for (int nt = 0; nt < 16; nt++) {
            floatx4 a = __builtin_amdgcn_mfma_f32_16x16x32_f16(af0, vf[nt][0], zero4, 0, 0, 0);
            acc[nt]   = __builtin_amdgcn_mfma_f32_16x16x32_f16(af1, vf[nt][1], a,     0, 0, 0);
        }

        // dedup: quad q writes nt in {4q..4q+3}; col = 16nt+lr = 64q+16i+lr
        #pragma unroll
        for (int i = 0; i < 4; i++) {
            float v01 = (q & 1) ? acc[4 + i][0]  : acc[i][0];
            float v23 = (q & 1) ? acc[12 + i][0] : acc[8 + i][0];
            float v   = (q & 2) ? v23 : v01;
            part[w][64 * q + 16 * i + lr] = v;
        }

        LDS_BARRIER();   // partials visible to all waves

        // cross-wave reduce: thread tid owns col tid
        float s = (part[0][tid] + part[1][tid]) + (part[2][tid] + part[3][tid]) + xu_cur;
        float e = __expf(2.f * s);
        float h = 1.f - __fdividef(2.f, e + 1.f);
        hbuf[p ^ 1][tid] = (_Float16)h;
        outDec[(size_t)t * HIDn + tid] = h;

        xu_cur = xu_nx;
        xu_nx  = pf;
        p ^= 1;
        LDS_BARRIER();   // h + part reusable; globals stay in flight
    }
}

extern "C" void kernel_launch(void* const* d_in, const int* in_sizes, int n_in,
                              void* d_out, int out_size, void* d_ws, size_t ws_size,
                              hipStream_t stream) {
    const float* enc  = (const float*)d_in[0];   // [256,256]
    const float* x    = (const float*)d_in[1];   // [256,512,256]
    const float* U    = (const float*)d_in[2];   // [256,256]
    const float* V    = (const float*)d_in[3];   // [256,256]
    const float* bias = (const float*)d_in[4];   // [256]
    float* out = (float*)d_out;                  // 65536 + 33554432 floats

    float* outDec = out + 65536;

    // bf16 B-frag scratch (128 KB): d_ws, or the 256 KB encoder-output region
    // of d_out as fallback (rnn_rec overwrites it only after xu_gemm is done).
    short* wsB = (ws_size >= 131072) ? (short*)d_ws : (short*)out;

    prep_B<<<32, 256, 0, stream>>>(U, wsB);

    xu_gemm<<<1024, 256, 0, stream>>>(x, wsB, bias, outDec);

    rnn_rec<<<256, 256, 0, stream>>>(enc, V, out);
}

// Round 4
// 486.187 us; speedup vs baseline: 1.2561x; 1.2561x over previous
//
#include <hip/hip_runtime.h>
#include <hip/hip_bf16.h>

// DecoderBlock: h_t = tanh(x_t @ U + h_{t-1} @ V + b)
// BZ=256, SEQ=512, IN=HID=256. fp32 in/out.
//
// SINGLE FUSED KERNEL this round. 1 WG per batch row, 512 thr (8 waves).
// Seq processed in 8 chunks of 64 steps:
//   phase A: stage x[b][t0:t0+64][:] -> LDS fp16 (XOR-swizzled 16B groups),
//            redundancy-free 64x256x256 MFMA GEMM with in-register U frags,
//            XU written to padded LDS buffer (bias folded in).
//   phase B: 64 recurrence steps: h@V via broadcast-A fp16 MFMA (R2 core),
//            xu read from LDS (no global loads in the loop at all),
//            LDS-only barrier (1/step), fire-and-forget h stores.
// Deletes prep_B + xu_gemm kernels and the 134MB XU HBM write + 134MB read.

#define SEQn   512
#define HIDn   256
#define CHUNK  64
#define NCHUNK 8

typedef __attribute__((ext_vector_type(4))) float    floatx4;
typedef __attribute__((ext_vector_type(8))) _Float16 half8;

// LDS-only barrier: drain LDS ops, then sync. Global ops stay in flight.
#define LDS_BARRIER() asm volatile("s_waitcnt lgkmcnt(0)\n\ts_barrier" ::: "memory")

__global__ __launch_bounds__(512, 1)
void rnn_fused(const float* __restrict__ enc, const float* __restrict__ x,
               const float* __restrict__ U,   const float* __restrict__ V,
               const float* __restrict__ bias, float* __restrict__ out)
{
    __shared__ _Float16 xbf[CHUNK][HIDn];     // 32 KB; 16B-group ^= (row&7)
    __shared__ float    xu[CHUNK][HIDn + 1];  // ~65.8 KB; +1 pad -> bank = (row+col)&31
    __shared__ _Float16 hbuf[2][HIDn];        // 1 KB ping-pong

    const int tid = threadIdx.x;
    const int w   = tid >> 6;        // wave 0..7
    const int l   = tid & 63;
    const int lr  = l & 15;
    const int q   = l >> 4;
    const int b   = blockIdx.x;
    const int c0  = 32 * w + lr;     // wave's first owned column

    // ---- preload U,V as fp16 B-fragments: uf/vf[nt][c][j] = M[32c+8q+j][c0+16nt]
    // 2 x 16 frags x 4 VGPR = 128 VGPRs total.
    half8 uf[2][8], vf[2][8];
    #pragma unroll
    for (int c = 0; c < 8; c++) {
        const float* up = U + (size_t)(32 * c + 8 * q) * HIDn + c0;
        const float* vp = V + (size_t)(32 * c + 8 * q) * HIDn + c0;
        #pragma unroll
        for (int nt = 0; nt < 2; nt++) {
            half8 tu, tv;
            #pragma unroll
            for (int j = 0; j < 8; j++) {
                tu[j] = (_Float16)up[(size_t)j * HIDn + 16 * nt];
                tv[j] = (_Float16)vp[(size_t)j * HIDn + 16 * nt];
            }
            uf[nt][c] = tu;
            vf[nt][c] = tv;
        }
    }

    const float b0 = bias[c0];
    const float b1 = bias[c0 + 16];

    // ---- h0 init + encoder passthrough ----
    if (tid < HIDn) {
        float h0 = enc[(size_t)b * HIDn + tid];
        out[(size_t)b * HIDn + tid] = h0;
        hbuf[0][tid] = (_Float16)h0;
    }

    const float* xb = x + (size_t)b * SEQn * HIDn;
    float* outDec   = out + (size_t)65536 + (size_t)b * SEQn * HIDn;

    const int srow = tid >> 3;         // staging row 0..63
    const int scol = (tid & 7) * 32;   // 32 consecutive floats per thread

    const floatx4 zf = {0.f, 0.f, 0.f, 0.f};

    int p = 0;
    for (int g = 0; g < NCHUNK; g++) {
        // ================= phase A1: stage x chunk as fp16 =================
        const float* xs = xb + (size_t)(g * CHUNK + srow) * HIDn + scol;
        float4 xv[8];
        #pragma unroll
        for (int i = 0; i < 8; i++)
            xv[i] = *(const float4*)(xs + 4 * i);
        #pragma unroll
        for (int gi = 0; gi < 4; gi++) {
            half8 t;
            t[0] = (_Float16)xv[2*gi].x;   t[1] = (_Float16)xv[2*gi].y;
            t[2] = (_Float16)xv[2*gi].z;   t[3] = (_Float16)xv[2*gi].w;
            t[4] = (_Float16)xv[2*gi+1].x; t[5] = (_Float16)xv[2*gi+1].y;
            t[6] = (_Float16)xv[2*gi+1].z; t[7] = (_Float16)xv[2*gi+1].w;
            int grp = ((tid & 7) * 4 + gi) ^ (srow & 7);
            *(half8*)&xbf[srow][grp * 8] = t;
        }
        LDS_BARRIER();

        // ====== phase A2: GEMM  xu[step][col] = x_chunk @ U + bias ======
        // wave w: cols {c0, c0+16}, all 4 m-tiles, K=256 (8 chunks).
        {
            floatx4 ga[2][4];
            #pragma unroll
            for (int c = 0; c < 8; c++) {
                half8 am[4];
                #pragma unroll
                for (int mt = 0; mt < 4; mt++) {
                    int row = 16 * mt + lr;
                    int grp = (4 * c + q) ^ (row & 7);
                    am[mt] = *(const half8*)&xbf[row][grp * 8];
                }
                #pragma unroll
                for (int mt = 0; mt < 4; mt++) {
                    ga[0][mt] = __builtin_amdgcn_mfma_f32_16x16x32_f16(
                        am[mt], uf[0][c], c ? ga[0][mt] : zf, 0, 0, 0);
                    ga[1][mt] = __builtin_amdgcn_mfma_f32_16x16x32_f16(
                        am[mt], uf[1][c], c ? ga[1][mt] : zf, 0, 0, 0);
                }
            }
            #pragma unroll
            for (int mt = 0; mt < 4; mt++)
                #pragma unroll
                for (int r = 0; r < 4; r++) {
                    int row = 16 * mt + 4 * q + r;   // chunk-local step
                    xu[row][c0]      = ga[0][mt][r] + b0;
                    xu[row][c0 + 16] = ga[1][mt][r] + b1;
                }
        }
        LDS_BARRIER();

        // ================= phase B: 64 recurrence steps =================
        for (int tt = 0; tt < CHUNK; tt++) {
            // A-frags: h broadcast to all 16 m-rows (quads read 16B chunks)
            half8 af[8];
            #pragma unroll
            for (int c = 0; c < 8; c++)
                af[c] = *(const half8*)&hbuf[p][32 * c + 8 * q];

            // 16 MFMAs as 8 chains of 2, seeded with zero (no acc-init movs)
            floatx4 acc[2][4];
            #pragma unroll
            for (int c = 0; c < 8; c++) {
                acc[0][c & 3] = __builtin_amdgcn_mfma_f32_16x16x32_f16(
                    af[c], vf[0][c], (c < 4) ? zf : acc[0][c & 3], 0, 0, 0);
                acc[1][c & 3] = __builtin_amdgcn_mfma_f32_16x16x32_f16(
                    af[c], vf[1][c], (c < 4) ? zf : acc[1][c & 3], 0, 0, 0);
            }

            float s0 = ((acc[0][0][0] + acc[0][1][0]) + (acc[0][2][0] + acc[0][3][0]))
                       + xu[tt][c0];
            float s1 = ((acc[1][0][0] + acc[1][1][0]) + (acc[1][2][0] + acc[1][3][0]))
                       + xu[tt][c0 + 16];
            float e0  = __expf(2.f * s0);
            float e1  = __expf(2.f * s1);
            float hv0 = 1.f - __fdividef(2.f, e0 + 1.f);
            float hv1 = 1.f - __fdividef(2.f, e1 + 1.f);

            if (q == 0) {   // quads 1-3 hold duplicates; one writer per column
                hbuf[p ^ 1][c0]      = (_Float16)hv0;
                hbuf[p ^ 1][c0 + 16] = (_Float16)hv1;
                float* op = outDec + (size_t)(g * CHUNK + tt) * HIDn;
                op[c0]      = hv0;       // fire-and-forget
                op[c0 + 16] = hv1;
            }
            p ^= 1;
            LDS_BARRIER();   // globals stay in flight
        }
    }
}

extern "C" void kernel_launch(void* const* d_in, const int* in_sizes, int n_in,
                              void* d_out, int out_size, void* d_ws, size_t ws_size,
                              hipStream_t stream) {
    const float* enc  = (const float*)d_in[0];   // [256,256]
    const float* x    = (const float*)d_in[1];   // [256,512,256]
    const float* U    = (const float*)d_in[2];   // [256,256]
    const float* V    = (const float*)d_in[3];   // [256,256]
    const float* bias = (const float*)d_in[4];   // [256]
    float* out = (float*)d_out;                  // 65536 + 33554432 floats

    rnn_fused<<<256, 512, 0, stream>>>(enc, x, U, V, bias, out);
}